// Round 1
// baseline (2856.163 us; speedup 1.0000x reference)
//
#include <hip/hip_runtime.h>
#include <math.h>

#define NSAMP 8
#define BATCH 1024
#define PH 12
#define XS 256
#define ZS 32
#define RNN 512
#define LSZ 8
#define LPS 2
#define INP 290          // LPS + ZS + XS
#define NTOT 8192        // NSAMP * BATCH
#define DT 0.4f

// output layout (flat f32, concatenated in return order)
#define LOGPI_OFF 0
#define MUS_OFF   (NTOT*PH)               // 98304
#define LSIG_OFF  (MUS_OFF + NTOT*PH*2)   // 294912
#define CORR_OFF  (LSIG_OFF + NTOT*PH*2)  // 491520
#define PRED_OFF  (CORR_OFF + NTOT*PH)    // 589824

__device__ __forceinline__ float sigmoid_(float x) {
    return 1.0f / (1.0f + __expf(-x));
}
__device__ __forceinline__ float tanh_(float x) {
    // tanh(x) = 1 - 2/(exp(2x)+1); handles +-inf limits correctly
    return 1.0f - 2.0f / (__expf(2.0f * x) + 1.0f);
}

// a0[n] = x_r_t0[n % B] @ W_sa.T + b_sa
__global__ void k_init_a(const float* __restrict__ x_r_t0,
                         const float* __restrict__ W_sa,
                         const float* __restrict__ b_sa,
                         float* __restrict__ a) {
    int n = blockIdx.x * blockDim.x + threadIdx.x;
    if (n >= NTOT) return;
    int b = n & (BATCH - 1);
    float a0 = b_sa[0], a1 = b_sa[1];
#pragma unroll
    for (int k = 0; k < LSZ; ++k) {
        float xv = x_r_t0[b * LSZ + k];
        a0 = fmaf(xv, W_sa[0 * LSZ + k], a0);
        a1 = fmaf(xv, W_sa[1 * LSZ + k], a1);
    }
    a[n * 2 + 0] = a0;
    a[n * 2 + 1] = a1;
}

// Combined GEMM: out cols 0..511 -> h0 = zx @ W_h0.T + b_h0
//                out cols 512..2047 -> gi_zx = zx @ W_ih[:, :288].T + b_ih
// zx[n] = [ z[n, 0:32], x[n % B, 0:256] ]
__global__ __launch_bounds__(256) void k_gemm0(
    const float* __restrict__ z, const float* __restrict__ x,
    const float* __restrict__ W_h0, const float* __restrict__ b_h0,
    const float* __restrict__ W_ih, const float* __restrict__ b_ih,
    float* __restrict__ h0, float* __restrict__ gi_zx)
{
    __shared__ float sIn[64][33];
    __shared__ float sW[64][33];
    const int tile_r = blockIdx.x * 64;
    const int tile_c = blockIdx.y * 64;
    const int tid = threadIdx.x;
    const int tx = tid & 15;   // col quad
    const int ty = tid >> 4;   // row quad
    float acc[4][4] = {};
    for (int k0 = 0; k0 < 288; k0 += 32) {
#pragma unroll
        for (int l = 0; l < 8; ++l) {
            int e = l * 256 + tid;
            int r = e >> 5, kk = e & 31;
            int rg = tile_r + r;
            float v;
            if (k0 == 0) v = z[rg * ZS + kk];
            else         v = x[(rg & (BATCH - 1)) * XS + (k0 - 32) + kk];
            sIn[r][kk] = v;
        }
#pragma unroll
        for (int l = 0; l < 8; ++l) {
            int e = l * 256 + tid;
            int c = e >> 5, kk = e & 31;
            int cg = tile_c + c;
            float v;
            if (cg < RNN) v = W_h0[cg * 288 + k0 + kk];
            else          v = W_ih[(cg - RNN) * INP + k0 + kk];
            sW[c][kk] = v;
        }
        __syncthreads();
#pragma unroll
        for (int kk = 0; kk < 32; ++kk) {
            float iv[4], wv[4];
#pragma unroll
            for (int i = 0; i < 4; ++i) iv[i] = sIn[ty * 4 + i][kk];
#pragma unroll
            for (int j = 0; j < 4; ++j) wv[j] = sW[tx * 4 + j][kk];
#pragma unroll
            for (int i = 0; i < 4; ++i)
#pragma unroll
                for (int j = 0; j < 4; ++j)
                    acc[i][j] = fmaf(iv[i], wv[j], acc[i][j]);
        }
        __syncthreads();
    }
#pragma unroll
    for (int i = 0; i < 4; ++i) {
        int rg = tile_r + ty * 4 + i;
#pragma unroll
        for (int j = 0; j < 4; ++j) {
            int cg = tile_c + tx * 4 + j;
            if (cg < RNN) h0[rg * RNN + cg] = acc[i][j] + b_h0[cg];
            else gi_zx[rg * 1536 + (cg - RNN)] = acc[i][j] + b_ih[cg - RNN];
        }
    }
}

// Fused GRU step: h_new = GRUCell(inp=[zx, a], h)
// gh = h @ W_hh.T (3 gates, computed here); gi = gi_zx + a @ W_ih[:,288:290].T
#define HSTR 34   // LDS row stride (floats): 2*HSTR % 32 == 4 -> at most 2-way conflicts (free)
__global__ __launch_bounds__(256) void k_gru_step(
    const float* __restrict__ h, const float* __restrict__ a,
    const float* __restrict__ gi_zx,
    const float* __restrict__ W_hh, const float* __restrict__ b_hh,
    const float* __restrict__ W_ih,
    float* __restrict__ h_new)
{
    __shared__ float hs[64][HSTR];
    __shared__ float ws[3][32][HSTR];
    const int tile_r = blockIdx.x * 64;
    const int tile_c = blockIdx.y * 32;
    const int tid = threadIdx.x;
    const int tx = tid & 15;   // col pair: cols tx*2 + {0,1}
    const int ty = tid >> 4;   // rows ty*4 + {0..3}
    float acc[3][4][2] = {};

    for (int k0 = 0; k0 < RNN; k0 += 32) {
        // h tile 64x32: 1024 float2 / 256 threads = 4 each
#pragma unroll
        for (int l = 0; l < 4; ++l) {
            int e = l * 256 + tid;
            int r = e >> 4, q = e & 15;
            const float2 v = *reinterpret_cast<const float2*>(&h[(tile_r + r) * RNN + k0 + q * 2]);
            *reinterpret_cast<float2*>(&hs[r][q * 2]) = v;
        }
        // W tiles 3x32x32: 1536 float2 / 256 = 6 each
#pragma unroll
        for (int l = 0; l < 6; ++l) {
            int e = l * 256 + tid;
            int g = e >> 9;
            int c = (e >> 4) & 31;
            int q = e & 15;
            const float2 v = *reinterpret_cast<const float2*>(
                &W_hh[(g * RNN + tile_c + c) * RNN + k0 + q * 2]);
            *reinterpret_cast<float2*>(&ws[g][c][q * 2]) = v;
        }
        __syncthreads();
#pragma unroll
        for (int kk = 0; kk < 32; ++kk) {
            float hv[4];
#pragma unroll
            for (int i = 0; i < 4; ++i) hv[i] = hs[ty * 4 + i][kk];
#pragma unroll
            for (int j = 0; j < 2; ++j) {
                int c = tx * 2 + j;
#pragma unroll
                for (int g = 0; g < 3; ++g) {
                    float wv = ws[g][c][kk];
#pragma unroll
                    for (int i = 0; i < 4; ++i)
                        acc[g][i][j] = fmaf(hv[i], wv, acc[g][i][j]);
                }
            }
        }
        __syncthreads();
    }

#pragma unroll
    for (int j = 0; j < 2; ++j) {
        const int cg = tile_c + tx * 2 + j;
        const float bh_r = b_hh[cg];
        const float bh_z = b_hh[RNN + cg];
        const float bh_n = b_hh[2 * RNN + cg];
        const float wr0 = W_ih[cg * INP + 288],             wr1 = W_ih[cg * INP + 289];
        const float wz0 = W_ih[(RNN + cg) * INP + 288],     wz1 = W_ih[(RNN + cg) * INP + 289];
        const float wn0 = W_ih[(2 * RNN + cg) * INP + 288], wn1 = W_ih[(2 * RNN + cg) * INP + 289];
#pragma unroll
        for (int i = 0; i < 4; ++i) {
            const int rg = tile_r + ty * 4 + i;
            const float a0 = a[rg * 2 + 0], a1 = a[rg * 2 + 1];
            const float gi_r = gi_zx[rg * 1536 + cg]            + a0 * wr0 + a1 * wr1;
            const float gi_z = gi_zx[rg * 1536 + RNN + cg]      + a0 * wz0 + a1 * wz1;
            const float gi_n = gi_zx[rg * 1536 + 2 * RNN + cg]  + a0 * wn0 + a1 * wn1;
            const float r_ = sigmoid_(gi_r + acc[0][i][j] + bh_r);
            const float u_ = sigmoid_(gi_z + acc[1][i][j] + bh_z);
            const float n_ = tanh_(gi_n + r_ * (acc[2][i][j] + bh_n));
            const float hv = h[rg * RNN + cg];
            h_new[rg * RNN + cg] = (1.0f - u_) * n_ + u_ * hv;
        }
    }
}

// Heads: one wave per row. mus/log_sigmas/corrs -> d_out; sample a_t -> a buffer
__global__ __launch_bounds__(256) void k_heads(
    const float* __restrict__ h_new,
    const float* __restrict__ W_mu, const float* __restrict__ b_mu,
    const float* __restrict__ W_ls, const float* __restrict__ b_ls,
    const float* __restrict__ W_corr, const float* __restrict__ b_corr,
    const float* __restrict__ eps_step_t,
    float* __restrict__ out, float* __restrict__ a, int t)
{
    const int wid = (blockIdx.x * blockDim.x + threadIdx.x) >> 6; // row
    const int lane = threadIdx.x & 63;
    if (wid >= NTOT) return;
    const int kbase = lane * 8;
    float hv[8];
    {
        const float4 v0 = *reinterpret_cast<const float4*>(&h_new[wid * RNN + kbase]);
        const float4 v1 = *reinterpret_cast<const float4*>(&h_new[wid * RNN + kbase + 4]);
        hv[0] = v0.x; hv[1] = v0.y; hv[2] = v0.z; hv[3] = v0.w;
        hv[4] = v1.x; hv[5] = v1.y; hv[6] = v1.z; hv[7] = v1.w;
    }
    float s0 = 0.f, s1 = 0.f, s2 = 0.f, s3 = 0.f, s4 = 0.f;
#pragma unroll
    for (int q = 0; q < 8; ++q) {
        int k = kbase + q;
        s0 = fmaf(hv[q], W_mu[k], s0);
        s1 = fmaf(hv[q], W_mu[RNN + k], s1);
        s2 = fmaf(hv[q], W_ls[k], s2);
        s3 = fmaf(hv[q], W_ls[RNN + k], s3);
        s4 = fmaf(hv[q], W_corr[k], s4);
    }
#pragma unroll
    for (int m = 32; m >= 1; m >>= 1) {
        s0 += __shfl_xor(s0, m, 64);
        s1 += __shfl_xor(s1, m, 64);
        s2 += __shfl_xor(s2, m, 64);
        s3 += __shfl_xor(s3, m, 64);
        s4 += __shfl_xor(s4, m, 64);
    }
    if (lane == 0) {
        const int n = wid;
        const float mu0 = s0 + b_mu[0], mu1 = s1 + b_mu[1];
        const float ls0 = s2 + b_ls[0], ls1 = s3 + b_ls[1];
        const float rho = tanh_(s4 + b_corr[0]);
        out[MUS_OFF + (n * PH + t) * 2 + 0] = mu0;
        out[MUS_OFF + (n * PH + t) * 2 + 1] = mu1;
        out[LSIG_OFF + (n * PH + t) * 2 + 0] = ls0;
        out[LSIG_OFF + (n * PH + t) * 2 + 1] = ls1;
        out[CORR_OFF + n * PH + t] = rho;
        const float e0 = eps_step_t[n * 2 + 0], e1 = eps_step_t[n * 2 + 1];
        const float sg0 = __expf(ls0), sg1 = __expf(ls1);
        const float dx = sg0 * e0;
        const float dy = sg1 * (rho * e0 + sqrtf(fmaxf(1e-5f, 1.0f - rho * rho)) * e1);
        a[n * 2 + 0] = mu0 + dx;
        a[n * 2 + 1] = mu1 + dy;
    }
}

// Final: a_sample from (mus, ls, corr, eps_final), cumsum -> preds; log_pis = 1
__global__ void k_final(const float* __restrict__ p0,
                        const float* __restrict__ eps_final,
                        float* __restrict__ out)
{
    int n = blockIdx.x * blockDim.x + threadIdx.x;
    if (n >= NTOT) return;
    const int b = n & (BATCH - 1);
    const float px = p0[b * 2 + 0], py = p0[b * 2 + 1];
    float cx = 0.f, cy = 0.f;
#pragma unroll
    for (int t = 0; t < PH; ++t) {
        const float mu0 = out[MUS_OFF + (n * PH + t) * 2 + 0];
        const float mu1 = out[MUS_OFF + (n * PH + t) * 2 + 1];
        const float ls0 = out[LSIG_OFF + (n * PH + t) * 2 + 0];
        const float ls1 = out[LSIG_OFF + (n * PH + t) * 2 + 1];
        const float rho = out[CORR_OFF + n * PH + t];
        const float e0 = eps_final[(n * PH + t) * 2 + 0];
        const float e1 = eps_final[(n * PH + t) * 2 + 1];
        const float sg0 = __expf(ls0), sg1 = __expf(ls1);
        const float ax = mu0 + sg0 * e0;
        const float ay = mu1 + sg1 * (rho * e0 + sqrtf(fmaxf(1e-5f, 1.0f - rho * rho)) * e1);
        cx += ax; cy += ay;
        out[PRED_OFF + (n * PH + t) * 2 + 0] = cx * DT + px;
        out[PRED_OFF + (n * PH + t) * 2 + 1] = cy * DT + py;
        out[LOGPI_OFF + n * PH + t] = 1.0f;
    }
}

extern "C" void kernel_launch(void* const* d_in, const int* in_sizes, int n_in,
                              void* d_out, int out_size, void* d_ws, size_t ws_size,
                              hipStream_t stream) {
    const float* x        = (const float*)d_in[0];
    const float* x_r_t0   = (const float*)d_in[1];
    const float* z        = (const float*)d_in[2];
    const float* p0       = (const float*)d_in[3];
    const float* eps_step = (const float*)d_in[4];
    const float* eps_fin  = (const float*)d_in[5];
    const float* W_sa     = (const float*)d_in[6];
    const float* b_sa     = (const float*)d_in[7];
    const float* W_ih     = (const float*)d_in[8];
    const float* b_ih     = (const float*)d_in[9];
    const float* W_hh     = (const float*)d_in[10];
    const float* b_hh     = (const float*)d_in[11];
    const float* W_h0     = (const float*)d_in[12];
    const float* b_h0     = (const float*)d_in[13];
    const float* W_mu     = (const float*)d_in[14];
    const float* b_mu     = (const float*)d_in[15];
    const float* W_ls     = (const float*)d_in[16];
    const float* b_ls     = (const float*)d_in[17];
    const float* W_corr   = (const float*)d_in[18];
    const float* b_corr   = (const float*)d_in[19];

    float* ws = (float*)d_ws;
    float* a     = ws;                         // N*2
    float* hbuf0 = ws + 2 * NTOT;              // N*512
    float* hbuf1 = hbuf0 + NTOT * RNN;         // N*512
    float* gi_zx = hbuf1 + NTOT * RNN;         // N*1536
    float* out = (float*)d_out;

    k_init_a<<<dim3(NTOT / 256), dim3(256), 0, stream>>>(x_r_t0, W_sa, b_sa, a);
    k_gemm0<<<dim3(128, 32), dim3(256), 0, stream>>>(z, x, W_h0, b_h0, W_ih, b_ih, hbuf0, gi_zx);

    float* hc = hbuf0;
    float* hn = hbuf1;
    for (int t = 0; t < PH; ++t) {
        k_gru_step<<<dim3(NTOT / 64, RNN / 32), dim3(256), 0, stream>>>(
            hc, a, gi_zx, W_hh, b_hh, W_ih, hn);
        k_heads<<<dim3(NTOT * 64 / 256), dim3(256), 0, stream>>>(
            hn, W_mu, b_mu, W_ls, b_ls, W_corr, b_corr,
            eps_step + (size_t)t * NTOT * 2, out, a, t);
        float* tmp = hc; hc = hn; hn = tmp;
    }
    k_final<<<dim3(NTOT / 256), dim3(256), 0, stream>>>(p0, eps_fin, out);
}

// Round 2
// 638.044 us; speedup vs baseline: 4.4764x; 4.4764x over previous
//
#include <hip/hip_runtime.h>
#include <hip/hip_bf16.h>
#include <math.h>

#define NSAMP 8
#define BATCH 1024
#define PH 12
#define XS 256
#define ZS 32
#define RNN 512
#define LSZ 8
#define INP 290          // LPS + ZS + XS
#define NTOT 8192        // NSAMP * BATCH
#define DT 0.4f

// output layout (flat f32, concatenated in return order)
#define LOGPI_OFF 0
#define MUS_OFF   (NTOT*PH)               // 98304
#define LSIG_OFF  (MUS_OFF + NTOT*PH*2)   // 294912
#define CORR_OFF  (LSIG_OFF + NTOT*PH*2)  // 491520
#define PRED_OFF  (CORR_OFF + NTOT*PH)    // 589824

typedef float f32x4 __attribute__((ext_vector_type(4)));
typedef __bf16 bf16x8 __attribute__((ext_vector_type(8)));

__device__ __forceinline__ float sigmoid_(float x) {
    return 1.0f / (1.0f + __expf(-x));
}
__device__ __forceinline__ float tanh_(float x) {
    return 1.0f - 2.0f / (__expf(2.0f * x) + 1.0f);
}

__device__ __forceinline__ void async16(const void* g, void* l) {
    __builtin_amdgcn_global_load_lds((const __attribute__((address_space(1))) void*)g,
                                     (__attribute__((address_space(3))) void*)l, 16, 0, 0);
}

// ---------------- small prep kernels ----------------

__global__ void k_init_a(const float* __restrict__ x_r_t0,
                         const float* __restrict__ W_sa,
                         const float* __restrict__ b_sa,
                         float* __restrict__ a) {
    int n = blockIdx.x * blockDim.x + threadIdx.x;
    if (n >= NTOT) return;
    int b = n & (BATCH - 1);
    float a0 = b_sa[0], a1 = b_sa[1];
#pragma unroll
    for (int k = 0; k < LSZ; ++k) {
        float xv = x_r_t0[b * LSZ + k];
        a0 = fmaf(xv, W_sa[0 * LSZ + k], a0);
        a1 = fmaf(xv, W_sa[1 * LSZ + k], a1);
    }
    a[n * 2 + 0] = a0;
    a[n * 2 + 1] = a1;
}

// zx_bf16[n][288] = [z[n,0:32], x[n%B,0:256]]
__global__ void k_cast_zx(const float* __restrict__ z, const float* __restrict__ x,
                          __hip_bfloat16* __restrict__ zx) {
    int n = blockIdx.x, k = threadIdx.x;
    if (k >= 288) return;
    float v = (k < 32) ? z[n * ZS + k] : x[(n & (BATCH - 1)) * XS + (k - 32)];
    zx[(size_t)n * 288 + k] = __float2bfloat16(v);
}

// Wcat[2048][288]: rows<512 = W_h0, rows>=512 = W_ih[:, :288] (stride 290)
__global__ void k_cast_w(const float* __restrict__ W_h0, const float* __restrict__ W_ih,
                         __hip_bfloat16* __restrict__ Wcat) {
    int r = blockIdx.x, k = threadIdx.x;
    if (k >= 288) return;
    float v = (r < RNN) ? W_h0[r * 288 + k] : W_ih[(size_t)(r - RNN) * INP + k];
    Wcat[(size_t)r * 288 + k] = __float2bfloat16(v);
}

__global__ void k_cast_whh(const float* __restrict__ W, __hip_bfloat16* __restrict__ Wb) {
    int i = blockIdx.x * 256 + threadIdx.x;   // grid covers 1536*512
    Wb[i] = __float2bfloat16(W[i]);
}

// ---------------- GEMM0: [h0 | gi_zx] = zx @ Wcat^T + bias ----------------
// M=8192, N=2048, K=288. 128x128 tile, 4 waves (2x2), wave tile 64x64.
__global__ __launch_bounds__(256, 2) void k_gemm0_mfma(
    const __hip_bfloat16* __restrict__ zx, const __hip_bfloat16* __restrict__ Wcat,
    const float* __restrict__ b_h0, const float* __restrict__ b_ih,
    __hip_bfloat16* __restrict__ h0, __hip_bfloat16* __restrict__ gi)
{
    __shared__ __align__(16) char sA[8192];   // [128][32] bf16, slot-swizzled
    __shared__ __align__(16) char sB[8192];
    const int tid = threadIdx.x;
    const int wv = tid >> 6, lane = tid & 63;
    const int fq = lane >> 4, fr = lane & 15;
    const int wr = wv >> 1, wc = wv & 1;
    const int tile_r = blockIdx.x * 128, tile_c = blockIdx.y * 128;

    f32x4 acc[4][4];
#pragma unroll
    for (int i = 0; i < 4; ++i)
#pragma unroll
        for (int j = 0; j < 4; ++j) acc[i][j] = (f32x4){0.f, 0.f, 0.f, 0.f};

    for (int k0 = 0; k0 < 288; k0 += 32) {
#pragma unroll
        for (int j = 0; j < 2; ++j) {
            int ck = wv * 2 + j;
            int row = ck * 16 + (lane >> 2);
            int slot = lane & 3;
            async16(zx + (size_t)(tile_r + row) * 288 + k0 + ((slot ^ (row & 3)) << 3),
                    sA + ck * 1024 + lane * 16);
        }
#pragma unroll
        for (int j = 0; j < 2; ++j) {
            int ck = wv * 2 + j;
            int row = ck * 16 + (lane >> 2);
            int slot = lane & 3;
            async16(Wcat + (size_t)(tile_c + row) * 288 + k0 + ((slot ^ (row & 3)) << 3),
                    sB + ck * 1024 + lane * 16);
        }
        __syncthreads();
        bf16x8 af[4], bv[4];
#pragma unroll
        for (int i = 0; i < 4; ++i) {
            int r = wr * 64 + i * 16 + fr;
            af[i] = *(const bf16x8*)(sA + r * 64 + ((fq ^ (r & 3)) << 4));
        }
#pragma unroll
        for (int j = 0; j < 4; ++j) {
            int r = wc * 64 + j * 16 + fr;
            bv[j] = *(const bf16x8*)(sB + r * 64 + ((fq ^ (r & 3)) << 4));
        }
#pragma unroll
        for (int i = 0; i < 4; ++i)
#pragma unroll
            for (int j = 0; j < 4; ++j)
                acc[i][j] = __builtin_amdgcn_mfma_f32_16x16x32_bf16(af[i], bv[j], acc[i][j], 0, 0, 0);
        __syncthreads();
    }

#pragma unroll
    for (int jn = 0; jn < 4; ++jn) {
        int cg = tile_c + wc * 64 + jn * 16 + fr;
        float bias = (cg < RNN) ? b_h0[cg] : b_ih[cg - RNN];
#pragma unroll
        for (int i = 0; i < 4; ++i)
#pragma unroll
            for (int q = 0; q < 4; ++q) {
                int rg = tile_r + wr * 64 + i * 16 + fq * 4 + q;
                float v = acc[i][jn][q] + bias;
                if (cg < RNN) h0[(size_t)rg * RNN + cg] = __float2bfloat16(v);
                else          gi[(size_t)rg * 1536 + (cg - RNN)] = __float2bfloat16(v);
            }
    }
}

// ---------------- fused GRU step (MFMA) ----------------
// Block: 128 rows x 64 h-cols x 3 gates. 4 waves 2x2 -> wave = 64 rows x 32 cols x 3 gates.
__global__ __launch_bounds__(256, 2) void k_gru_step_mfma(
    const __hip_bfloat16* __restrict__ h, const float* __restrict__ a,
    const __hip_bfloat16* __restrict__ gi,
    const __hip_bfloat16* __restrict__ Whh, const float* __restrict__ b_hh,
    const float* __restrict__ W_ih,
    __hip_bfloat16* __restrict__ h_new)
{
    __shared__ __align__(16) char sA[8192];    // [128][32] bf16
    __shared__ __align__(16) char sB[12288];   // [3][64][32] bf16
    const int tid = threadIdx.x;
    const int wv = tid >> 6, lane = tid & 63;
    const int fq = lane >> 4, fr = lane & 15;
    const int wr = wv >> 1, wc = wv & 1;
    const int tile_r = blockIdx.x * 128;
    const int tile_c = blockIdx.y * 64;        // h-state column base (0..511)

    f32x4 acc[3][4][2];
#pragma unroll
    for (int g = 0; g < 3; ++g)
#pragma unroll
        for (int i = 0; i < 4; ++i)
#pragma unroll
            for (int j = 0; j < 2; ++j) acc[g][i][j] = (f32x4){0.f, 0.f, 0.f, 0.f};

    for (int k0 = 0; k0 < RNN; k0 += 32) {
#pragma unroll
        for (int j = 0; j < 2; ++j) {
            int ck = wv * 2 + j;
            int row = ck * 16 + (lane >> 2);
            int slot = lane & 3;
            async16(h + (size_t)(tile_r + row) * RNN + k0 + ((slot ^ (row & 3)) << 3),
                    sA + ck * 1024 + lane * 16);
        }
#pragma unroll
        for (int j = 0; j < 3; ++j) {
            int bc = wv * 3 + j;
            int g = bc >> 2, rb = bc & 3;
            int row = rb * 16 + (lane >> 2);
            int slot = lane & 3;
            async16(Whh + (size_t)(g * RNN + tile_c + row) * RNN + k0 + ((slot ^ (row & 3)) << 3),
                    sB + bc * 1024 + lane * 16);
        }
        __syncthreads();
        bf16x8 af[4];
#pragma unroll
        for (int i = 0; i < 4; ++i) {
            int r = wr * 64 + i * 16 + fr;
            af[i] = *(const bf16x8*)(sA + r * 64 + ((fq ^ (r & 3)) << 4));
        }
        bf16x8 bv[3][2];
#pragma unroll
        for (int g = 0; g < 3; ++g)
#pragma unroll
            for (int j = 0; j < 2; ++j) {
                int r = wc * 32 + j * 16 + fr;
                bv[g][j] = *(const bf16x8*)(sB + g * 4096 + r * 64 + ((fq ^ (r & 3)) << 4));
            }
#pragma unroll
        for (int g = 0; g < 3; ++g)
#pragma unroll
            for (int i = 0; i < 4; ++i)
#pragma unroll
                for (int j = 0; j < 2; ++j)
                    acc[g][i][j] = __builtin_amdgcn_mfma_f32_16x16x32_bf16(af[i], bv[g][j], acc[g][i][j], 0, 0, 0);
        __syncthreads();
    }

    // fused GRU epilogue
#pragma unroll
    for (int j = 0; j < 2; ++j) {
        const int cg = tile_c + wc * 32 + j * 16 + fr;
        const float bh_r = b_hh[cg], bh_z = b_hh[RNN + cg], bh_n = b_hh[2 * RNN + cg];
        const float wr0 = W_ih[(size_t)cg * INP + 288],             wr1 = W_ih[(size_t)cg * INP + 289];
        const float wz0 = W_ih[(size_t)(RNN + cg) * INP + 288],     wz1 = W_ih[(size_t)(RNN + cg) * INP + 289];
        const float wn0 = W_ih[(size_t)(2 * RNN + cg) * INP + 288], wn1 = W_ih[(size_t)(2 * RNN + cg) * INP + 289];
#pragma unroll
        for (int i = 0; i < 4; ++i)
#pragma unroll
            for (int q = 0; q < 4; ++q) {
                const int rg = tile_r + wr * 64 + i * 16 + fq * 4 + q;
                const float2 av = *(const float2*)&a[rg * 2];
                const float gr = __bfloat162float(gi[(size_t)rg * 1536 + cg])
                                 + av.x * wr0 + av.y * wr1 + acc[0][i][j][q] + bh_r;
                const float gz = __bfloat162float(gi[(size_t)rg * 1536 + RNN + cg])
                                 + av.x * wz0 + av.y * wz1 + acc[1][i][j][q] + bh_z;
                const float gn = __bfloat162float(gi[(size_t)rg * 1536 + 2 * RNN + cg])
                                 + av.x * wn0 + av.y * wn1;
                const float r_ = sigmoid_(gr);
                const float u_ = sigmoid_(gz);
                const float n_ = tanh_(gn + r_ * (acc[2][i][j][q] + bh_n));
                const float hv = __bfloat162float(h[(size_t)rg * RNN + cg]);
                h_new[(size_t)rg * RNN + cg] = __float2bfloat16((1.0f - u_) * n_ + u_ * hv);
            }
    }
}

// ---------------- heads: one wave per row ----------------
__global__ __launch_bounds__(256) void k_heads(
    const __hip_bfloat16* __restrict__ h_new,
    const float* __restrict__ W_mu, const float* __restrict__ b_mu,
    const float* __restrict__ W_ls, const float* __restrict__ b_ls,
    const float* __restrict__ W_corr, const float* __restrict__ b_corr,
    const float* __restrict__ eps_step_t,
    float* __restrict__ out, float* __restrict__ a, int t)
{
    const int wid = (blockIdx.x * blockDim.x + threadIdx.x) >> 6;
    const int lane = threadIdx.x & 63;
    if (wid >= NTOT) return;
    const int kbase = lane * 8;
    float hv[8];
    {
        uint4 v = *reinterpret_cast<const uint4*>(&h_new[(size_t)wid * RNN + kbase]);
        unsigned uu[4] = {v.x, v.y, v.z, v.w};
#pragma unroll
        for (int p = 0; p < 4; ++p) {
            hv[2 * p]     = __uint_as_float(uu[p] << 16);
            hv[2 * p + 1] = __uint_as_float(uu[p] & 0xffff0000u);
        }
    }
    float s0 = 0.f, s1 = 0.f, s2 = 0.f, s3 = 0.f, s4 = 0.f;
#pragma unroll
    for (int q = 0; q < 8; ++q) {
        int k = kbase + q;
        s0 = fmaf(hv[q], W_mu[k], s0);
        s1 = fmaf(hv[q], W_mu[RNN + k], s1);
        s2 = fmaf(hv[q], W_ls[k], s2);
        s3 = fmaf(hv[q], W_ls[RNN + k], s3);
        s4 = fmaf(hv[q], W_corr[k], s4);
    }
#pragma unroll
    for (int m = 32; m >= 1; m >>= 1) {
        s0 += __shfl_xor(s0, m, 64);
        s1 += __shfl_xor(s1, m, 64);
        s2 += __shfl_xor(s2, m, 64);
        s3 += __shfl_xor(s3, m, 64);
        s4 += __shfl_xor(s4, m, 64);
    }
    if (lane == 0) {
        const int n = wid;
        const float mu0 = s0 + b_mu[0], mu1 = s1 + b_mu[1];
        const float ls0 = s2 + b_ls[0], ls1 = s3 + b_ls[1];
        const float rho = tanh_(s4 + b_corr[0]);
        out[MUS_OFF + (n * PH + t) * 2 + 0] = mu0;
        out[MUS_OFF + (n * PH + t) * 2 + 1] = mu1;
        out[LSIG_OFF + (n * PH + t) * 2 + 0] = ls0;
        out[LSIG_OFF + (n * PH + t) * 2 + 1] = ls1;
        out[CORR_OFF + n * PH + t] = rho;
        const float e0 = eps_step_t[n * 2 + 0], e1 = eps_step_t[n * 2 + 1];
        const float sg0 = __expf(ls0), sg1 = __expf(ls1);
        a[n * 2 + 0] = mu0 + sg0 * e0;
        a[n * 2 + 1] = mu1 + sg1 * (rho * e0 + sqrtf(fmaxf(1e-5f, 1.0f - rho * rho)) * e1);
    }
}

// ---------------- final: sample + cumsum + log_pis ----------------
__global__ void k_final(const float* __restrict__ p0,
                        const float* __restrict__ eps_final,
                        float* __restrict__ out)
{
    int n = blockIdx.x * blockDim.x + threadIdx.x;
    if (n >= NTOT) return;
    const int b = n & (BATCH - 1);
    const float px = p0[b * 2 + 0], py = p0[b * 2 + 1];
    float cx = 0.f, cy = 0.f;
#pragma unroll
    for (int t = 0; t < PH; ++t) {
        const float mu0 = out[MUS_OFF + (n * PH + t) * 2 + 0];
        const float mu1 = out[MUS_OFF + (n * PH + t) * 2 + 1];
        const float ls0 = out[LSIG_OFF + (n * PH + t) * 2 + 0];
        const float ls1 = out[LSIG_OFF + (n * PH + t) * 2 + 1];
        const float rho = out[CORR_OFF + n * PH + t];
        const float e0 = eps_final[(n * PH + t) * 2 + 0];
        const float e1 = eps_final[(n * PH + t) * 2 + 1];
        const float sg0 = __expf(ls0), sg1 = __expf(ls1);
        cx += mu0 + sg0 * e0;
        cy += mu1 + sg1 * (rho * e0 + sqrtf(fmaxf(1e-5f, 1.0f - rho * rho)) * e1);
        out[PRED_OFF + (n * PH + t) * 2 + 0] = cx * DT + px;
        out[PRED_OFF + (n * PH + t) * 2 + 1] = cy * DT + py;
        out[LOGPI_OFF + n * PH + t] = 1.0f;
    }
}

extern "C" void kernel_launch(void* const* d_in, const int* in_sizes, int n_in,
                              void* d_out, int out_size, void* d_ws, size_t ws_size,
                              hipStream_t stream) {
    const float* x        = (const float*)d_in[0];
    const float* x_r_t0   = (const float*)d_in[1];
    const float* z        = (const float*)d_in[2];
    const float* p0       = (const float*)d_in[3];
    const float* eps_step = (const float*)d_in[4];
    const float* eps_fin  = (const float*)d_in[5];
    const float* W_sa     = (const float*)d_in[6];
    const float* b_sa     = (const float*)d_in[7];
    const float* W_ih     = (const float*)d_in[8];
    const float* b_ih     = (const float*)d_in[9];
    const float* W_hh     = (const float*)d_in[10];
    const float* b_hh     = (const float*)d_in[11];
    const float* W_h0     = (const float*)d_in[12];
    const float* b_h0     = (const float*)d_in[13];
    const float* W_mu     = (const float*)d_in[14];
    const float* b_mu     = (const float*)d_in[15];
    const float* W_ls     = (const float*)d_in[16];
    const float* b_ls     = (const float*)d_in[17];
    const float* W_corr   = (const float*)d_in[18];
    const float* b_corr   = (const float*)d_in[19];

    char* wp = (char*)d_ws;
    float* a            = (float*)wp;          wp += (size_t)NTOT * 2 * 4;
    __hip_bfloat16* zxb = (__hip_bfloat16*)wp; wp += (size_t)NTOT * 288 * 2;
    __hip_bfloat16* Wcat= (__hip_bfloat16*)wp; wp += (size_t)2048 * 288 * 2;
    __hip_bfloat16* Whhb= (__hip_bfloat16*)wp; wp += (size_t)1536 * RNN * 2;
    __hip_bfloat16* h0  = (__hip_bfloat16*)wp; wp += (size_t)NTOT * RNN * 2;
    __hip_bfloat16* h1  = (__hip_bfloat16*)wp; wp += (size_t)NTOT * RNN * 2;
    __hip_bfloat16* gi  = (__hip_bfloat16*)wp; wp += (size_t)NTOT * 1536 * 2;
    float* out = (float*)d_out;

    k_init_a<<<dim3(NTOT / 256), dim3(256), 0, stream>>>(x_r_t0, W_sa, b_sa, a);
    k_cast_zx<<<dim3(NTOT), dim3(320), 0, stream>>>(z, x, zxb);
    k_cast_w<<<dim3(2048), dim3(320), 0, stream>>>(W_h0, W_ih, Wcat);
    k_cast_whh<<<dim3(1536 * RNN / 256), dim3(256), 0, stream>>>(W_hh, Whhb);
    k_gemm0_mfma<<<dim3(64, 16), dim3(256), 0, stream>>>(zxb, Wcat, b_h0, b_ih, h0, gi);

    __hip_bfloat16* hc = h0;
    __hip_bfloat16* hn = h1;
    for (int t = 0; t < PH; ++t) {
        k_gru_step_mfma<<<dim3(NTOT / 128, RNN / 64), dim3(256), 0, stream>>>(
            hc, a, gi, Whhb, b_hh, W_ih, hn);
        k_heads<<<dim3(NTOT * 64 / 256), dim3(256), 0, stream>>>(
            hn, W_mu, b_mu, W_ls, b_ls, W_corr, b_corr,
            eps_step + (size_t)t * NTOT * 2, out, a, t);
        __hip_bfloat16* tmp = hc; hc = hn; hn = tmp;
    }
    k_final<<<dim3(NTOT / 256), dim3(256), 0, stream>>>(p0, eps_fin, out);
}

// Round 4
// 422.450 us; speedup vs baseline: 6.7609x; 1.5103x over previous
//
#include <hip/hip_runtime.h>
#include <hip/hip_bf16.h>
#include <math.h>

#define NSAMP 8
#define BATCH 1024
#define PH 12
#define XS 256
#define ZS 32
#define RNN 512
#define LSZ 8
#define INP 290          // LPS + ZS + XS
#define NTOT 8192        // NSAMP * BATCH
#define DT 0.4f

// output layout (flat f32, concatenated in return order)
#define LOGPI_OFF 0
#define MUS_OFF   (NTOT*PH)               // 98304
#define LSIG_OFF  (MUS_OFF + NTOT*PH*2)   // 294912
#define CORR_OFF  (LSIG_OFF + NTOT*PH*2)  // 491520
#define PRED_OFF  (CORR_OFF + NTOT*PH)    // 589824

typedef float f32x4 __attribute__((ext_vector_type(4)));
typedef __bf16 bf16x8 __attribute__((ext_vector_type(8)));

__device__ __forceinline__ float sigmoid_(float x) {
    return 1.0f / (1.0f + __expf(-x));
}
__device__ __forceinline__ float tanh_(float x) {
    return 1.0f - 2.0f / (__expf(2.0f * x) + 1.0f);
}

__device__ __forceinline__ void async16(const void* g, void* l) {
    __builtin_amdgcn_global_load_lds((const __attribute__((address_space(1))) void*)g,
                                     (__attribute__((address_space(3))) void*)l, 16, 0, 0);
}

// ---------------- small prep kernels ----------------

__global__ void k_init_a(const float* __restrict__ x_r_t0,
                         const float* __restrict__ W_sa,
                         const float* __restrict__ b_sa,
                         float* __restrict__ a) {
    int n = blockIdx.x * blockDim.x + threadIdx.x;
    if (n >= NTOT) return;
    int b = n & (BATCH - 1);
    float a0 = b_sa[0], a1 = b_sa[1];
#pragma unroll
    for (int k = 0; k < LSZ; ++k) {
        float xv = x_r_t0[b * LSZ + k];
        a0 = fmaf(xv, W_sa[0 * LSZ + k], a0);
        a1 = fmaf(xv, W_sa[1 * LSZ + k], a1);
    }
    a[n * 2 + 0] = a0;
    a[n * 2 + 1] = a1;
}

// zx_bf16[n][288] = [z[n,0:32], x[n%B,0:256]]
__global__ void k_cast_zx(const float* __restrict__ z, const float* __restrict__ x,
                          __hip_bfloat16* __restrict__ zx) {
    int n = blockIdx.x, k = threadIdx.x;
    if (k >= 288) return;
    float v = (k < 32) ? z[n * ZS + k] : x[(n & (BATCH - 1)) * XS + (k - 32)];
    zx[(size_t)n * 288 + k] = __float2bfloat16(v);
}

// Wcat[2048][288]: rows<512 = W_h0, rows>=512 = W_ih[:, :288] (stride 290)
__global__ void k_cast_w(const float* __restrict__ W_h0, const float* __restrict__ W_ih,
                         __hip_bfloat16* __restrict__ Wcat) {
    int r = blockIdx.x, k = threadIdx.x;
    if (k >= 288) return;
    float v = (r < RNN) ? W_h0[r * 288 + k] : W_ih[(size_t)(r - RNN) * INP + k];
    Wcat[(size_t)r * 288 + k] = __float2bfloat16(v);
}

__global__ void k_cast_whh(const float* __restrict__ W, __hip_bfloat16* __restrict__ Wb) {
    int i = blockIdx.x * 256 + threadIdx.x;   // grid covers 1536*512
    Wb[i] = __float2bfloat16(W[i]);
}

// ---------------- GEMM0: [h0 | gi_zx] = zx @ Wcat^T + bias ----------------
// M=8192, N=2048, K=288. 128x128 tile, 4 waves (2x2), wave tile 64x64.
__global__ __launch_bounds__(256, 2) void k_gemm0_mfma(
    const __hip_bfloat16* __restrict__ zx, const __hip_bfloat16* __restrict__ Wcat,
    const float* __restrict__ b_h0, const float* __restrict__ b_ih,
    __hip_bfloat16* __restrict__ h0, __hip_bfloat16* __restrict__ gi)
{
    __shared__ __align__(16) char sA[8192];   // [128][32] bf16, slot-swizzled
    __shared__ __align__(16) char sB[8192];
    const int tid = threadIdx.x;
    const int wv = tid >> 6, lane = tid & 63;
    const int fq = lane >> 4, fr = lane & 15;
    const int wr = wv >> 1, wc = wv & 1;
    const int tile_r = blockIdx.x * 128, tile_c = blockIdx.y * 128;

    f32x4 acc[4][4];
#pragma unroll
    for (int i = 0; i < 4; ++i)
#pragma unroll
        for (int j = 0; j < 4; ++j) acc[i][j] = (f32x4){0.f, 0.f, 0.f, 0.f};

    for (int k0 = 0; k0 < 288; k0 += 32) {
#pragma unroll
        for (int j = 0; j < 2; ++j) {
            int ck = wv * 2 + j;
            int row = ck * 16 + (lane >> 2);
            int slot = lane & 3;
            async16(zx + (size_t)(tile_r + row) * 288 + k0 + ((slot ^ (row & 3)) << 3),
                    sA + ck * 1024 + lane * 16);
        }
#pragma unroll
        for (int j = 0; j < 2; ++j) {
            int ck = wv * 2 + j;
            int row = ck * 16 + (lane >> 2);
            int slot = lane & 3;
            async16(Wcat + (size_t)(tile_c + row) * 288 + k0 + ((slot ^ (row & 3)) << 3),
                    sB + ck * 1024 + lane * 16);
        }
        __syncthreads();
        bf16x8 af[4], bv[4];
#pragma unroll
        for (int i = 0; i < 4; ++i) {
            int r = wr * 64 + i * 16 + fr;
            af[i] = *(const bf16x8*)(sA + r * 64 + ((fq ^ (r & 3)) << 4));
        }
#pragma unroll
        for (int j = 0; j < 4; ++j) {
            int r = wc * 64 + j * 16 + fr;
            bv[j] = *(const bf16x8*)(sB + r * 64 + ((fq ^ (r & 3)) << 4));
        }
#pragma unroll
        for (int i = 0; i < 4; ++i)
#pragma unroll
            for (int j = 0; j < 4; ++j)
                acc[i][j] = __builtin_amdgcn_mfma_f32_16x16x32_bf16(af[i], bv[j], acc[i][j], 0, 0, 0);
        __syncthreads();
    }

#pragma unroll
    for (int jn = 0; jn < 4; ++jn) {
        int cg = tile_c + wc * 64 + jn * 16 + fr;
        float bias = (cg < RNN) ? b_h0[cg] : b_ih[cg - RNN];
#pragma unroll
        for (int i = 0; i < 4; ++i)
#pragma unroll
            for (int q = 0; q < 4; ++q) {
                int rg = tile_r + wr * 64 + i * 16 + fq * 4 + q;
                float v = acc[i][jn][q] + bias;
                if (cg < RNN) h0[(size_t)rg * RNN + cg] = __float2bfloat16(v);
                else          gi[(size_t)rg * 1536 + (cg - RNN)] = __float2bfloat16(v);
            }
    }
}

// ---------------- fused GRU step (MFMA, 2-phase double-buffered) ----------------
// Block: 256 rows x 64 h-cols x 3 gates. 8 waves (4x2) -> wave = 64 rows x (32 cols x 3 gates).
#define GRU_LDS_A 32768
#define GRU_LDS_BUF 57344
__global__ __launch_bounds__(512, 2) void k_gru_step_mfma(
    const __hip_bfloat16* __restrict__ h, const float* __restrict__ a,
    const __hip_bfloat16* __restrict__ gi,
    const __hip_bfloat16* __restrict__ Whh, const float* __restrict__ b_hh,
    const float* __restrict__ W_ih,
    __hip_bfloat16* __restrict__ h_new)
{
    __shared__ __align__(16) char lds[2][GRU_LDS_BUF];
    const int tid = threadIdx.x;
    const int wv = tid >> 6, lane = tid & 63;
    const int fq = lane >> 4, fr = lane & 15;
    const int wr = wv >> 1, wc = wv & 1;          // wr 0..3 (64-row strips), wc 0..1 (32-col strips)
    const int tile_r = blockIdx.x * 256;
    const int tile_c = blockIdx.y * 64;           // h-state column base (0..511)

    f32x4 acc[3][4][2];
#pragma unroll
    for (int g = 0; g < 3; ++g)
#pragma unroll
        for (int i = 0; i < 4; ++i)
#pragma unroll
            for (int j = 0; j < 2; ++j) acc[g][i][j] = (f32x4){0.f, 0.f, 0.f, 0.f};

    const int lrow = lane >> 2;                   // row within 16-row chunk
    const int slot = (lane & 3) ^ (lrow & 3);     // XOR slot swizzle (both sides)

    // stage one BK=64 tile pair into buffer b: 56 chunks, 7 per wave
    auto stage = [&](int b, int k0) {
#pragma unroll
        for (int j = 0; j < 7; ++j) {
            int c = wv * 7 + j;
            if (c < 32) {
                int rowgrp = c >> 1, kh = c & 1;
                int row = tile_r + rowgrp * 16 + lrow;
                async16(h + (size_t)row * RNN + k0 + kh * 32 + slot * 8,
                        lds[b] + c * 1024 + lane * 16);
            } else {
                int cp = c - 32;
                int grp = cp >> 1, kh = cp & 1;
                int rB = grp * 16 + lrow;          // 0..191
                int gate = rB >> 6, col = rB & 63;
                async16(Whh + (size_t)(gate * RNN + tile_c + col) * RNN + k0 + kh * 32 + slot * 8,
                        lds[b] + GRU_LDS_A + cp * 1024 + lane * 16);
            }
        }
    };

    auto compute = [&](int b) {
        const char* bufA = lds[b];
        const char* bufB = lds[b] + GRU_LDS_A;
        const int rsw = (fq ^ (fr & 3)) << 4;     // read-side swizzle
#pragma unroll
        for (int ks = 0; ks < 2; ++ks) {
            bf16x8 af[4];
#pragma unroll
            for (int i = 0; i < 4; ++i) {
                int chunk = (wr * 4 + i) * 2 + ks;
                af[i] = *(const bf16x8*)(bufA + chunk * 1024 + fr * 64 + rsw);
            }
            bf16x8 bv[3][2];
#pragma unroll
            for (int g = 0; g < 3; ++g)
#pragma unroll
                for (int j = 0; j < 2; ++j) {
                    int grp = g * 4 + wc * 2 + j;
                    int chunk = grp * 2 + ks;
                    bv[g][j] = *(const bf16x8*)(bufB + chunk * 1024 + fr * 64 + rsw);
                }
#pragma unroll
            for (int g = 0; g < 3; ++g)
#pragma unroll
                for (int i = 0; i < 4; ++i)
#pragma unroll
                    for (int j = 0; j < 2; ++j)
                        acc[g][i][j] = __builtin_amdgcn_mfma_f32_16x16x32_bf16(
                            af[i], bv[g][j], acc[g][i][j], 0, 0, 0);
        }
    };

    stage(0, 0);
    __syncthreads();
    int buf = 0;
#pragma unroll 1
    for (int t = 0; t < 7; ++t) {
        stage(buf ^ 1, (t + 1) * 64);   // issue next-tile loads BEFORE compute
        compute(buf);
        __syncthreads();                 // drain after full compute phase
        buf ^= 1;
    }
    compute(buf);

    // fused GRU epilogue
#pragma unroll
    for (int j = 0; j < 2; ++j) {
        const int cg = tile_c + wc * 32 + j * 16 + fr;
        const float bh_r = b_hh[cg], bh_z = b_hh[RNN + cg], bh_n = b_hh[2 * RNN + cg];
        const float wr0 = W_ih[(size_t)cg * INP + 288],             wr1 = W_ih[(size_t)cg * INP + 289];
        const float wz0 = W_ih[(size_t)(RNN + cg) * INP + 288],     wz1 = W_ih[(size_t)(RNN + cg) * INP + 289];
        const float wn0 = W_ih[(size_t)(2 * RNN + cg) * INP + 288], wn1 = W_ih[(size_t)(2 * RNN + cg) * INP + 289];
#pragma unroll
        for (int i = 0; i < 4; ++i)
#pragma unroll
            for (int q = 0; q < 4; ++q) {
                const int rg = tile_r + wr * 64 + i * 16 + fq * 4 + q;
                const float2 av = *(const float2*)&a[rg * 2];
                const float gr = __bfloat162float(gi[(size_t)rg * 1536 + cg])
                                 + av.x * wr0 + av.y * wr1 + acc[0][i][j][q] + bh_r;
                const float gz = __bfloat162float(gi[(size_t)rg * 1536 + RNN + cg])
                                 + av.x * wz0 + av.y * wz1 + acc[1][i][j][q] + bh_z;
                const float gn = __bfloat162float(gi[(size_t)rg * 1536 + 2 * RNN + cg])
                                 + av.x * wn0 + av.y * wn1;
                const float r_ = sigmoid_(gr);
                const float u_ = sigmoid_(gz);
                const float n_ = tanh_(gn + r_ * (acc[2][i][j][q] + bh_n));
                const float hv = __bfloat162float(h[(size_t)rg * RNN + cg]);
                h_new[(size_t)rg * RNN + cg] = __float2bfloat16((1.0f - u_) * n_ + u_ * hv);
            }
    }
}

// ---------------- heads: one wave per row ----------------
__global__ __launch_bounds__(256) void k_heads(
    const __hip_bfloat16* __restrict__ h_new,
    const float* __restrict__ W_mu, const float* __restrict__ b_mu,
    const float* __restrict__ W_ls, const float* __restrict__ b_ls,
    const float* __restrict__ W_corr, const float* __restrict__ b_corr,
    const float* __restrict__ eps_step_t,
    float* __restrict__ out, float* __restrict__ a, int t)
{
    const int wid = (blockIdx.x * blockDim.x + threadIdx.x) >> 6;
    const int lane = threadIdx.x & 63;
    if (wid >= NTOT) return;
    const int kbase = lane * 8;
    float hv[8];
    {
        uint4 v = *reinterpret_cast<const uint4*>(&h_new[(size_t)wid * RNN + kbase]);
        unsigned uu[4] = {v.x, v.y, v.z, v.w};
#pragma unroll
        for (int p = 0; p < 4; ++p) {
            hv[2 * p]     = __uint_as_float(uu[p] << 16);
            hv[2 * p + 1] = __uint_as_float(uu[p] & 0xffff0000u);
        }
    }
    float s0 = 0.f, s1 = 0.f, s2 = 0.f, s3 = 0.f, s4 = 0.f;
#pragma unroll
    for (int q = 0; q < 8; ++q) {
        int k = kbase + q;
        s0 = fmaf(hv[q], W_mu[k], s0);
        s1 = fmaf(hv[q], W_mu[RNN + k], s1);
        s2 = fmaf(hv[q], W_ls[k], s2);
        s3 = fmaf(hv[q], W_ls[RNN + k], s3);
        s4 = fmaf(hv[q], W_corr[k], s4);
    }
#pragma unroll
    for (int m = 32; m >= 1; m >>= 1) {
        s0 += __shfl_xor(s0, m, 64);
        s1 += __shfl_xor(s1, m, 64);
        s2 += __shfl_xor(s2, m, 64);
        s3 += __shfl_xor(s3, m, 64);
        s4 += __shfl_xor(s4, m, 64);
    }
    if (lane == 0) {
        const int n = wid;
        const float mu0 = s0 + b_mu[0], mu1 = s1 + b_mu[1];
        const float ls0 = s2 + b_ls[0], ls1 = s3 + b_ls[1];
        const float rho = tanh_(s4 + b_corr[0]);
        out[MUS_OFF + (n * PH + t) * 2 + 0] = mu0;
        out[MUS_OFF + (n * PH + t) * 2 + 1] = mu1;
        out[LSIG_OFF + (n * PH + t) * 2 + 0] = ls0;
        out[LSIG_OFF + (n * PH + t) * 2 + 1] = ls1;
        out[CORR_OFF + n * PH + t] = rho;
        const float e0 = eps_step_t[n * 2 + 0], e1 = eps_step_t[n * 2 + 1];
        const float sg0 = __expf(ls0), sg1 = __expf(ls1);
        a[n * 2 + 0] = mu0 + sg0 * e0;
        a[n * 2 + 1] = mu1 + sg1 * (rho * e0 + sqrtf(fmaxf(1e-5f, 1.0f - rho * rho)) * e1);
    }
}

// ---------------- final: sample + cumsum + log_pis ----------------
__global__ void k_final(const float* __restrict__ p0,
                        const float* __restrict__ eps_final,
                        float* __restrict__ out)
{
    int n = blockIdx.x * blockDim.x + threadIdx.x;
    if (n >= NTOT) return;
    const int b = n & (BATCH - 1);
    const float px = p0[b * 2 + 0], py = p0[b * 2 + 1];
    float cx = 0.f, cy = 0.f;
#pragma unroll
    for (int t = 0; t < PH; ++t) {
        const float mu0 = out[MUS_OFF + (n * PH + t) * 2 + 0];
        const float mu1 = out[MUS_OFF + (n * PH + t) * 2 + 1];
        const float ls0 = out[LSIG_OFF + (n * PH + t) * 2 + 0];
        const float ls1 = out[LSIG_OFF + (n * PH + t) * 2 + 1];
        const float rho = out[CORR_OFF + n * PH + t];
        const float e0 = eps_final[(n * PH + t) * 2 + 0];
        const float e1 = eps_final[(n * PH + t) * 2 + 1];
        const float sg0 = __expf(ls0), sg1 = __expf(ls1);
        cx += mu0 + sg0 * e0;
        cy += mu1 + sg1 * (rho * e0 + sqrtf(fmaxf(1e-5f, 1.0f - rho * rho)) * e1);
        out[PRED_OFF + (n * PH + t) * 2 + 0] = cx * DT + px;
        out[PRED_OFF + (n * PH + t) * 2 + 1] = cy * DT + py;
        out[LOGPI_OFF + n * PH + t] = 1.0f;
    }
}

extern "C" void kernel_launch(void* const* d_in, const int* in_sizes, int n_in,
                              void* d_out, int out_size, void* d_ws, size_t ws_size,
                              hipStream_t stream) {
    const float* x        = (const float*)d_in[0];
    const float* x_r_t0   = (const float*)d_in[1];
    const float* z        = (const float*)d_in[2];
    const float* p0       = (const float*)d_in[3];
    const float* eps_step = (const float*)d_in[4];
    const float* eps_fin  = (const float*)d_in[5];
    const float* W_sa     = (const float*)d_in[6];
    const float* b_sa     = (const float*)d_in[7];
    const float* W_ih     = (const float*)d_in[8];
    const float* b_ih     = (const float*)d_in[9];
    const float* W_hh     = (const float*)d_in[10];
    const float* b_hh     = (const float*)d_in[11];
    const float* W_h0     = (const float*)d_in[12];
    const float* b_h0     = (const float*)d_in[13];
    const float* W_mu     = (const float*)d_in[14];
    const float* b_mu     = (const float*)d_in[15];
    const float* W_ls     = (const float*)d_in[16];
    const float* b_ls     = (const float*)d_in[17];
    const float* W_corr   = (const float*)d_in[18];
    const float* b_corr   = (const float*)d_in[19];

    char* wp = (char*)d_ws;
    float* a            = (float*)wp;          wp += (size_t)NTOT * 2 * 4;
    __hip_bfloat16* zxb = (__hip_bfloat16*)wp; wp += (size_t)NTOT * 288 * 2;
    __hip_bfloat16* Wcat= (__hip_bfloat16*)wp; wp += (size_t)2048 * 288 * 2;
    __hip_bfloat16* Whhb= (__hip_bfloat16*)wp; wp += (size_t)1536 * RNN * 2;
    __hip_bfloat16* h0  = (__hip_bfloat16*)wp; wp += (size_t)NTOT * RNN * 2;
    __hip_bfloat16* h1  = (__hip_bfloat16*)wp; wp += (size_t)NTOT * RNN * 2;
    __hip_bfloat16* gi  = (__hip_bfloat16*)wp; wp += (size_t)NTOT * 1536 * 2;
    float* out = (float*)d_out;

    k_init_a<<<dim3(NTOT / 256), dim3(256), 0, stream>>>(x_r_t0, W_sa, b_sa, a);
    k_cast_zx<<<dim3(NTOT), dim3(320), 0, stream>>>(z, x, zxb);
    k_cast_w<<<dim3(2048), dim3(320), 0, stream>>>(W_h0, W_ih, Wcat);
    k_cast_whh<<<dim3(1536 * RNN / 256), dim3(256), 0, stream>>>(W_hh, Whhb);
    k_gemm0_mfma<<<dim3(64, 16), dim3(256), 0, stream>>>(zxb, Wcat, b_h0, b_ih, h0, gi);

    __hip_bfloat16* hc = h0;
    __hip_bfloat16* hn = h1;
    for (int t = 0; t < PH; ++t) {
        k_gru_step_mfma<<<dim3(NTOT / 256, RNN / 64), dim3(512), 0, stream>>>(
            hc, a, gi, Whhb, b_hh, W_ih, hn);
        k_heads<<<dim3(NTOT * 64 / 256), dim3(256), 0, stream>>>(
            hn, W_mu, b_mu, W_ls, b_ls, W_corr, b_corr,
            eps_step + (size_t)t * NTOT * 2, out, a, t);
        __hip_bfloat16* tmp = hc; hc = hn; hn = tmp;
    }
    k_final<<<dim3(NTOT / 256), dim3(256), 0, stream>>>(p0, eps_fin, out);
}